// Round 7
// baseline (335.476 us; speedup 1.0000x reference)
//
#include <hip/hip_runtime.h>
#include <cmath>

// K[n,m] = sv^2 * sum_p (x1[n,p]-off)*(x2[m,p]-off) + sb^2,  N=M=8192, P=16.
// Output 256 MiB fp32, write-BW-bound (fill proves 6.5 TB/s on these boxes).
//
// Evidence through R6 (kernel-side = dur - ~162us fill):
//   R0 LDS-tile 128x128, burst stores, 16 waves/CU ........ 110 us  (best)
//   R2 streaming C-in-reg, interleaved stores, 16 w/CU ..... 128 us
//   R3 = R2 + nt stores + pipeline ......................... 137 us
//   R6 persistent 512-block lockstep sweep, 8 w/CU ......... 157 us (worst)
// -> Time tracks (a) resident wave count and (b) burst-vs-interleaved store
//    issue. Store topology / nt / LDS / pipelining all refuted pairwise.
//
// R7: keep R0's phase structure (stage -> rank-16 accumulate -> dense store
// burst) but DOUBLE occupancy: 64x64 tile, acc[4][4] per thread, target
// <=64 VGPR (__launch_bounds__(256,8)) -> 8 waves/SIMD = 32 waves/CU.
// LDS 2x 16x68 floats = 8.7 KB (not the occupancy limiter). sv is folded
// into the staged tiles (tile = sv*(x-off)), so dot gives sv^2*d directly
// and the epilogue is acc + sb2 -> 4x float4 burst stores.

typedef float f32x4 __attribute__((ext_vector_type(4)));

#define TILE 64
#define LDST 68   // padded stride (floats): 2-way bank alias on stage = free

__global__ __launch_bounds__(256, 8) void linear_kernel(
    const float* __restrict__ x1, const float* __restrict__ x2,
    const float* __restrict__ p_lsb, const float* __restrict__ p_lsv,
    const float* __restrict__ p_off, float* __restrict__ out, int m)
{
    __shared__ float s1[16 * LDST];  // s1[p*LDST + row] = sv*(x1[n0+row][p]-off)
    __shared__ float s2[16 * LDST];  // s2[p*LDST + row] = sv*(x2[m0+row][p]-off)

    const int tid = threadIdx.x;
    const int tx  = tid & 15;        // column group (4 cols)
    const int ty  = tid >> 4;        // row group (4 rows)
    const int n0  = blockIdx.y * TILE;
    const int m0  = blockIdx.x * TILE;

    const float off = p_off[0];
    const float sv  = expf(p_lsv[0]);
    const float sb  = expf(p_lsb[0]);
    const float sb2 = sb * sb;

    // ---- Stage: one float4 per thread per matrix, transposed + scaled ----
    {
        const int row = tid >> 2;          // 0..63
        const int q   = tid & 3;           // quad index
        const f32x4 v = ((const f32x4*)(x1 + (size_t)(n0 + row) * 16))[q];
        const f32x4 w = ((const f32x4*)(x2 + (size_t)(m0 + row) * 16))[q];
        #pragma unroll
        for (int j = 0; j < 4; ++j) {
            s1[(q * 4 + j) * LDST + row] = sv * (v[j] - off);
            s2[(q * 4 + j) * LDST + row] = sv * (w[j] - off);
        }
    }

    float acc[4][4];
    #pragma unroll
    for (int r = 0; r < 4; ++r)
        #pragma unroll
        for (int c = 0; c < 4; ++c) acc[r][c] = 0.0f;

    __syncthreads();

    // ---- Rank-16 accumulation: a4 broadcast, b4 contiguous (conflict-free) ----
    #pragma unroll
    for (int p = 0; p < 16; ++p) {
        const f32x4 a4 = *(const f32x4*)&s1[p * LDST + ty * 4];
        const f32x4 b4 = *(const f32x4*)&s2[p * LDST + tx * 4];
        #pragma unroll
        for (int r = 0; r < 4; ++r)
            #pragma unroll
            for (int c = 0; c < 4; ++c)
                acc[r][c] = fmaf(a4[r], b4[c], acc[r][c]);
    }

    // ---- Burst epilogue: 4 x float4 stores, ~1 VALU per element ----
    float* orow = out + (size_t)(n0 + ty * 4) * m + m0 + tx * 4;
    #pragma unroll
    for (int r = 0; r < 4; ++r) {
        f32x4 o;
        o[0] = acc[r][0] + sb2;
        o[1] = acc[r][1] + sb2;
        o[2] = acc[r][2] + sb2;
        o[3] = acc[r][3] + sb2;
        *(f32x4*)orow = o;
        orow += m;
    }
}

extern "C" void kernel_launch(void* const* d_in, const int* in_sizes, int n_in,
                              void* d_out, int out_size, void* d_ws, size_t ws_size,
                              hipStream_t stream) {
    const float* x1  = (const float*)d_in[0];
    const float* x2  = (const float*)d_in[1];
    const float* lsb = (const float*)d_in[2];
    const float* lsv = (const float*)d_in[3];
    const float* off = (const float*)d_in[4];
    float* out = (float*)d_out;

    const int n = in_sizes[0] / 16;   // 8192
    const int m = in_sizes[1] / 16;   // 8192

    dim3 grid(m / TILE, n / TILE);    // 128 x 128 = 16384 blocks
    linear_kernel<<<grid, 256, 0, stream>>>(x1, x2, lsb, lsv, off, out, m);
}